// Round 1
// baseline (467.161 us; speedup 1.0000x reference)
//
#include <hip/hip_runtime.h>
#include <hip/hip_bf16.h>

#define RES 7
#define NCH 256

// One block per (roi, bin). 256 threads = one channel each.
// All threads of a block share identical sample positions/weights; each
// thread gathers 16 fp32 taps from its channel plane and writes one output.
__global__ __launch_bounds__(256) void roi_align_fpn_kernel(
    const float* __restrict__ f0, const float* __restrict__ f1,
    const float* __restrict__ f2, const float* __restrict__ f3,
    const float* __restrict__ boxes, const int* __restrict__ bidx,
    float* __restrict__ out)
{
    const int r   = blockIdx.x;
    const int bin = blockIdx.y;
    const int c   = threadIdx.x;
    const int py  = bin / RES;
    const int px  = bin - py * RES;

    // ---- per-ROI params (computed redundantly per thread; cheap vs 16 gathers)
    const float bx1 = boxes[r * 4 + 0];
    const float by1 = boxes[r * 4 + 1];
    const float bx2 = boxes[r * 4 + 2];
    const float by2 = boxes[r * 4 + 3];

    const float area = fmaxf(bx2 - bx1, 0.0f) * fmaxf(by2 - by1, 0.0f);
    const float s    = sqrtf(area);
    const float lvlf = floorf(4.0f + log2f(s / 224.0f + 1e-6f));
    const int   lvl  = (int)(fminf(fmaxf(lvlf, 2.0f), 5.0f)) - 2;

    const float scales[4] = {0.25f, 0.125f, 0.0625f, 0.03125f};
    const int   Hs[4]     = {200, 100, 50, 25};
    const float* feats[4] = {f0, f1, f2, f3};

    const float scale = scales[lvl];
    const int   H     = Hs[lvl];
    const int   W     = H;
    const float* feat = feats[lvl];

    const int b = bidx[r];

    const float x1 = bx1 * scale;
    const float y1 = by1 * scale;
    const float roi_w = fmaxf(bx2 * scale - x1, 1.0f);
    const float roi_h = fmaxf(by2 * scale - y1, 1.0f);
    const float bw = roi_w * (1.0f / RES);
    const float bh = roi_h * (1.0f / RES);

    const float* __restrict__ fc = feat + (size_t)(b * NCH + c) * H * W;

    float acc = 0.0f;
#pragma unroll
    for (int sy = 0; sy < 2; ++sy) {
        const float pyf = (float)py + ((float)sy + 0.5f) * 0.5f;
        const float ys  = y1 + pyf * bh;
        const bool  vy  = (ys >= -1.0f) && (ys <= (float)H);
        const float ycl = fminf(fmaxf(ys, 0.0f), (float)(H - 1));
        const int   y0  = (int)floorf(ycl);
        const int   y1i = min(y0 + 1, H - 1);
        const float ly  = ycl - (float)y0;
        const float hy  = 1.0f - ly;
#pragma unroll
        for (int sx = 0; sx < 2; ++sx) {
            const float pxf = (float)px + ((float)sx + 0.5f) * 0.5f;
            const float xs  = x1 + pxf * bw;
            const bool  vx  = (xs >= -1.0f) && (xs <= (float)W);
            const float xcl = fminf(fmaxf(xs, 0.0f), (float)(W - 1));
            const int   x0  = (int)floorf(xcl);
            const int   x1i = min(x0 + 1, W - 1);
            const float lx  = xcl - (float)x0;
            const float hx  = 1.0f - lx;

            const float v00 = fc[y0  * W + x0 ];
            const float v01 = fc[y0  * W + x1i];
            const float v10 = fc[y1i * W + x0 ];
            const float v11 = fc[y1i * W + x1i];

            const float v = v00 * (hy * hx) + v01 * (hy * lx)
                          + v10 * (ly * hx) + v11 * (ly * lx);
            if (vy && vx) acc += v;
        }
    }

    out[((size_t)r * NCH + c) * (RES * RES) + bin] = acc * 0.25f;
}

extern "C" void kernel_launch(void* const* d_in, const int* in_sizes, int n_in,
                              void* d_out, int out_size, void* d_ws, size_t ws_size,
                              hipStream_t stream)
{
    const float* f0    = (const float*)d_in[0];
    const float* f1    = (const float*)d_in[1];
    const float* f2    = (const float*)d_in[2];
    const float* f3    = (const float*)d_in[3];
    const float* boxes = (const float*)d_in[4];
    const int*   bidx  = (const int*)d_in[5];
    float* out = (float*)d_out;

    const int R = in_sizes[4] / 4;  // 512 boxes

    dim3 grid(R, RES * RES);
    dim3 block(NCH);
    roi_align_fpn_kernel<<<grid, block, 0, stream>>>(f0, f1, f2, f3, boxes, bidx, out);
}

// Round 2
// 80.803 us; speedup vs baseline: 5.7814x; 5.7814x over previous
//
#include <hip/hip_runtime.h>
#include <hip/hip_bf16.h>

#define RES 7
#define NCH 256

// ---------------------------------------------------------------------------
// Pass 1: NCHW -> NHWC transpose per level. src (2,256,HW) -> dst (2,HW,256).
// Tiled 32x32 via LDS; both global read and write coalesced.
// ---------------------------------------------------------------------------
__global__ __launch_bounds__(256) void transpose_chw_hwc(
    const float* __restrict__ src, float* __restrict__ dst, int HW)
{
    __shared__ float tile[32][33];
    const int b   = blockIdx.z;
    const int hw0 = blockIdx.x * 32;
    const int c0  = blockIdx.y * 32;
    const int tx  = threadIdx.x;   // 0..31
    const int ty  = threadIdx.y;   // 0..7

    const float* __restrict__ s = src + (size_t)b * NCH * HW;
    float* __restrict__ d       = dst + (size_t)b * HW * NCH;

    const int hw_r = hw0 + tx;
#pragma unroll
    for (int i = 0; i < 32; i += 8) {
        const int c = c0 + ty + i;
        if (hw_r < HW) tile[ty + i][tx] = s[(size_t)c * HW + hw_r];
    }
    __syncthreads();
    const int c_w = c0 + tx;
#pragma unroll
    for (int i = 0; i < 32; i += 8) {
        const int hw = hw0 + ty + i;
        if (hw < HW) d[(size_t)hw * NCH + c_w] = tile[tx][ty + i];
    }
}

// ---------------------------------------------------------------------------
// Pass 2: one block per ROI; 256 threads = 256 channels.
// Gathers are contiguous across lanes (NHWC). Results staged in padded LDS,
// then the ROI's 256x49-float output block is written fully coalesced.
// ---------------------------------------------------------------------------
__global__ __launch_bounds__(256) void roi_gather_nhwc(
    const float* __restrict__ ws,
    const float* __restrict__ boxes, const int* __restrict__ bidx,
    float* __restrict__ out)
{
    __shared__ float lds[49 * 257];

    const int r = blockIdx.x;
    const int c = threadIdx.x;

    const float bx1 = boxes[r * 4 + 0];
    const float by1 = boxes[r * 4 + 1];
    const float bx2 = boxes[r * 4 + 2];
    const float by2 = boxes[r * 4 + 3];

    const float area = fmaxf(bx2 - bx1, 0.0f) * fmaxf(by2 - by1, 0.0f);
    const float s    = sqrtf(area);
    const float lvlf = floorf(4.0f + log2f(s / 224.0f + 1e-6f));
    const int   lvl  = (int)(fminf(fmaxf(lvlf, 2.0f), 5.0f)) - 2;

    // wave-uniform per block (same r) -> uniform branch, no divergence
    float scale; int H; size_t off;
    if      (lvl == 0) { scale = 0.25f;    H = 200; off = 0u; }
    else if (lvl == 1) { scale = 0.125f;   H = 100; off = 20480000u; }
    else if (lvl == 2) { scale = 0.0625f;  H = 50;  off = 25600000u; }
    else               { scale = 0.03125f; H = 25;  off = 26880000u; }
    const int W = H;

    const int b = bidx[r];
    const float* __restrict__ feat = ws + off + (size_t)b * H * W * NCH;

    const float x1 = bx1 * scale;
    const float y1 = by1 * scale;
    const float roi_w = fmaxf(bx2 * scale - x1, 1.0f);
    const float roi_h = fmaxf(by2 * scale - y1, 1.0f);
    const float bw = roi_w * (1.0f / RES);
    const float bh = roi_h * (1.0f / RES);

    for (int bin = 0; bin < 49; ++bin) {
        const int py = bin / 7;
        const int px = bin - py * 7;

        float acc = 0.0f;
#pragma unroll
        for (int sy = 0; sy < 2; ++sy) {
            const float pyf = (float)py + ((float)sy + 0.5f) * 0.5f;
            const float ysmp = y1 + pyf * bh;
            const bool  vy   = (ysmp >= -1.0f) && (ysmp <= (float)H);
            const float ycl  = fminf(fmaxf(ysmp, 0.0f), (float)(H - 1));
            const int   y0   = (int)floorf(ycl);
            const int   y1i  = min(y0 + 1, H - 1);
            const float ly   = ycl - (float)y0;
            const float hy   = 1.0f - ly;
#pragma unroll
            for (int sx = 0; sx < 2; ++sx) {
                const float pxf = (float)px + ((float)sx + 0.5f) * 0.5f;
                const float xsmp = x1 + pxf * bw;
                const bool  vx   = (xsmp >= -1.0f) && (xsmp <= (float)W);
                const float xcl  = fminf(fmaxf(xsmp, 0.0f), (float)(W - 1));
                const int   x0   = (int)floorf(xcl);
                const int   x1i  = min(x0 + 1, W - 1);
                const float lx   = xcl - (float)x0;
                const float hx   = 1.0f - lx;

                const float m = (vy && vx) ? 1.0f : 0.0f;

                const float v00 = feat[((size_t)(y0  * W + x0 )) * NCH + c];
                const float v01 = feat[((size_t)(y0  * W + x1i)) * NCH + c];
                const float v10 = feat[((size_t)(y1i * W + x0 )) * NCH + c];
                const float v11 = feat[((size_t)(y1i * W + x1i)) * NCH + c];

                acc += m * (v00 * (hy * hx) + v01 * (hy * lx)
                          + v10 * (ly * hx) + v11 * (ly * lx));
            }
        }
        lds[bin * 257 + c] = acc * 0.25f;
    }

    __syncthreads();

    // coalesced write of the ROI's contiguous 256*49-float block
    float* __restrict__ o = out + (size_t)r * (NCH * 49);
#pragma unroll
    for (int i = 0; i < 49; ++i) {
        const int j  = i * NCH + c;       // 0..12543
        const int ch = j / 49;
        const int bn = j - ch * 49;
        o[j] = lds[bn * 257 + ch];
    }
}

// ---------------------------------------------------------------------------
// Fallback (round-1 kernel) if d_ws is too small for the NHWC copy.
// ---------------------------------------------------------------------------
__global__ __launch_bounds__(256) void roi_align_fpn_kernel(
    const float* __restrict__ f0, const float* __restrict__ f1,
    const float* __restrict__ f2, const float* __restrict__ f3,
    const float* __restrict__ boxes, const int* __restrict__ bidx,
    float* __restrict__ out)
{
    const int r   = blockIdx.x;
    const int bin = blockIdx.y;
    const int c   = threadIdx.x;
    const int py  = bin / RES;
    const int px  = bin - py * RES;

    const float bx1 = boxes[r * 4 + 0];
    const float by1 = boxes[r * 4 + 1];
    const float bx2 = boxes[r * 4 + 2];
    const float by2 = boxes[r * 4 + 3];

    const float area = fmaxf(bx2 - bx1, 0.0f) * fmaxf(by2 - by1, 0.0f);
    const float s    = sqrtf(area);
    const float lvlf = floorf(4.0f + log2f(s / 224.0f + 1e-6f));
    const int   lvl  = (int)(fminf(fmaxf(lvlf, 2.0f), 5.0f)) - 2;

    const float scales[4] = {0.25f, 0.125f, 0.0625f, 0.03125f};
    const int   Hs[4]     = {200, 100, 50, 25};
    const float* feats[4] = {f0, f1, f2, f3};

    const float scale = scales[lvl];
    const int   H     = Hs[lvl];
    const int   W     = H;
    const float* feat = feats[lvl];

    const int b = bidx[r];

    const float x1 = bx1 * scale;
    const float y1 = by1 * scale;
    const float roi_w = fmaxf(bx2 * scale - x1, 1.0f);
    const float roi_h = fmaxf(by2 * scale - y1, 1.0f);
    const float bw = roi_w * (1.0f / RES);
    const float bh = roi_h * (1.0f / RES);

    const float* __restrict__ fc = feat + (size_t)(b * NCH + c) * H * W;

    float acc = 0.0f;
#pragma unroll
    for (int sy = 0; sy < 2; ++sy) {
        const float pyf = (float)py + ((float)sy + 0.5f) * 0.5f;
        const float ys  = y1 + pyf * bh;
        const bool  vy  = (ys >= -1.0f) && (ys <= (float)H);
        const float ycl = fminf(fmaxf(ys, 0.0f), (float)(H - 1));
        const int   y0  = (int)floorf(ycl);
        const int   y1i = min(y0 + 1, H - 1);
        const float ly  = ycl - (float)y0;
        const float hy  = 1.0f - ly;
#pragma unroll
        for (int sx = 0; sx < 2; ++sx) {
            const float pxf = (float)px + ((float)sx + 0.5f) * 0.5f;
            const float xs  = x1 + pxf * bw;
            const bool  vx  = (xs >= -1.0f) && (xs <= (float)W);
            const float xcl = fminf(fmaxf(xs, 0.0f), (float)(W - 1));
            const int   x0  = (int)floorf(xcl);
            const int   x1i = min(x0 + 1, W - 1);
            const float lx  = xcl - (float)x0;
            const float hx  = 1.0f - lx;

            const float v00 = fc[y0  * W + x0 ];
            const float v01 = fc[y0  * W + x1i];
            const float v10 = fc[y1i * W + x0 ];
            const float v11 = fc[y1i * W + x1i];

            const float v = v00 * (hy * hx) + v01 * (hy * lx)
                          + v10 * (ly * hx) + v11 * (ly * lx);
            if (vy && vx) acc += v;
        }
    }

    out[((size_t)r * NCH + c) * (RES * RES) + bin] = acc * 0.25f;
}

extern "C" void kernel_launch(void* const* d_in, const int* in_sizes, int n_in,
                              void* d_out, int out_size, void* d_ws, size_t ws_size,
                              hipStream_t stream)
{
    const float* f0    = (const float*)d_in[0];
    const float* f1    = (const float*)d_in[1];
    const float* f2    = (const float*)d_in[2];
    const float* f3    = (const float*)d_in[3];
    const float* boxes = (const float*)d_in[4];
    const int*   bidx  = (const int*)d_in[5];
    float* out = (float*)d_out;

    const int R = in_sizes[4] / 4;  // 512 boxes

    const size_t need = 27200000ull * sizeof(float);  // NHWC copy of all levels

    if (ws_size >= need) {
        float* ws = (float*)d_ws;
        // level offsets (floats): 0, 20480000, 25600000, 26880000
        const int HWs[4]  = {40000, 10000, 2500, 625};
        const float* srcs[4] = {f0, f1, f2, f3};
        const size_t offs[4] = {0u, 20480000u, 25600000u, 26880000u};
        for (int l = 0; l < 4; ++l) {
            dim3 grid((HWs[l] + 31) / 32, NCH / 32, 2);
            dim3 block(32, 8);
            transpose_chw_hwc<<<grid, block, 0, stream>>>(srcs[l], ws + offs[l], HWs[l]);
        }
        roi_gather_nhwc<<<dim3(R), dim3(NCH), 0, stream>>>(ws, boxes, bidx, out);
    } else {
        dim3 grid(R, RES * RES);
        roi_align_fpn_kernel<<<grid, dim3(NCH), 0, stream>>>(f0, f1, f2, f3, boxes, bidx, out);
    }
}

// Round 3
// 64.604 us; speedup vs baseline: 7.2311x; 1.2507x over previous
//
#include <hip/hip_runtime.h>
#include <hip/hip_bf16.h>

#define RES 7
#define NCH 256

__device__ __forceinline__ unsigned short f32_to_bf16_rne(float f) {
    unsigned int u = __float_as_uint(f);
    u += 0x7fffu + ((u >> 16) & 1u);
    return (unsigned short)(u >> 16);
}

// ---------------------------------------------------------------------------
// Pass 1: NCHW fp32 -> NHWC bf16 transpose per level.
// src (2,256,HW) fp32 -> dst (2,HW,256) bf16. Tiled 32x32 via LDS.
// ---------------------------------------------------------------------------
__global__ __launch_bounds__(256) void transpose_chw_hwc_bf16(
    const float* __restrict__ src, unsigned short* __restrict__ dst, int HW)
{
    __shared__ float tile[32][33];
    const int b   = blockIdx.z;
    const int hw0 = blockIdx.x * 32;
    const int c0  = blockIdx.y * 32;
    const int tx  = threadIdx.x;   // 0..31
    const int ty  = threadIdx.y;   // 0..7

    const float* __restrict__ s     = src + (size_t)b * NCH * HW;
    unsigned short* __restrict__ d  = dst + (size_t)b * HW * NCH;

    const int hw_r = hw0 + tx;
#pragma unroll
    for (int i = 0; i < 32; i += 8) {
        const int c = c0 + ty + i;
        if (hw_r < HW) tile[ty + i][tx] = s[(size_t)c * HW + hw_r];
    }
    __syncthreads();
    const int c_w = c0 + tx;
#pragma unroll
    for (int i = 0; i < 32; i += 8) {
        const int hw = hw0 + ty + i;
        if (hw < HW) d[(size_t)hw * NCH + c_w] = f32_to_bf16_rne(tile[tx][ty + i]);
    }
}

// ---------------------------------------------------------------------------
// Pass 2: one block per ROI; 256 threads = 128 channel-pairs x 2 bin-halves.
// Each thread loads a uint (2 bf16 channels) per tap -> 256B/wave coalesced.
// Results staged in LDS, then the ROI's 256x49-float block written coalesced.
// ---------------------------------------------------------------------------
__global__ __launch_bounds__(256) void roi_gather_nhwc_bf16(
    const unsigned short* __restrict__ ws,
    const float* __restrict__ boxes, const int* __restrict__ bidx,
    float* __restrict__ out)
{
    __shared__ float lds[49 * 258];

    const int r    = blockIdx.x;
    const int t    = threadIdx.x;
    const int cp   = t & 127;      // channel pair index: channels 2cp, 2cp+1
    const int half = t >> 7;       // 0: bins 0..24, 1: bins 25..48

    const float bx1 = boxes[r * 4 + 0];
    const float by1 = boxes[r * 4 + 1];
    const float bx2 = boxes[r * 4 + 2];
    const float by2 = boxes[r * 4 + 3];

    const float area = fmaxf(bx2 - bx1, 0.0f) * fmaxf(by2 - by1, 0.0f);
    const float s    = sqrtf(area);
    const float lvlf = floorf(4.0f + log2f(s / 224.0f + 1e-6f));
    const int   lvl  = (int)(fminf(fmaxf(lvlf, 2.0f), 5.0f)) - 2;

    float scale; int H; size_t off;
    if      (lvl == 0) { scale = 0.25f;    H = 200; off = 0u; }
    else if (lvl == 1) { scale = 0.125f;   H = 100; off = 20480000u; }
    else if (lvl == 2) { scale = 0.0625f;  H = 50;  off = 25600000u; }
    else               { scale = 0.03125f; H = 25;  off = 26880000u; }
    const int W = H;

    const int b = bidx[r];
    const unsigned short* __restrict__ feat = ws + off + (size_t)b * H * W * NCH;

    const float x1 = bx1 * scale;
    const float y1 = by1 * scale;
    const float roi_w = fmaxf(bx2 * scale - x1, 1.0f);
    const float roi_h = fmaxf(by2 * scale - y1, 1.0f);
    const float bw = roi_w * (1.0f / RES);
    const float bh = roi_h * (1.0f / RES);

    const int bin_lo = half ? 25 : 0;
    const int bin_hi = half ? 49 : 25;

    for (int bin = bin_lo; bin < bin_hi; ++bin) {
        const int py = bin / 7;
        const int px = bin - py * 7;

        float acc0 = 0.0f, acc1 = 0.0f;
#pragma unroll
        for (int sy = 0; sy < 2; ++sy) {
            const float pyf = (float)py + ((float)sy + 0.5f) * 0.5f;
            const float ysmp = y1 + pyf * bh;
            const bool  vy   = (ysmp >= -1.0f) && (ysmp <= (float)H);
            const float ycl  = fminf(fmaxf(ysmp, 0.0f), (float)(H - 1));
            const int   y0   = (int)floorf(ycl);
            const int   y1i  = min(y0 + 1, H - 1);
            const float ly   = ycl - (float)y0;
            const float hy   = 1.0f - ly;
#pragma unroll
            for (int sx = 0; sx < 2; ++sx) {
                const float pxf = (float)px + ((float)sx + 0.5f) * 0.5f;
                const float xsmp = x1 + pxf * bw;
                const bool  vx   = (xsmp >= -1.0f) && (xsmp <= (float)W);
                const float xcl  = fminf(fmaxf(xsmp, 0.0f), (float)(W - 1));
                const int   x0   = (int)floorf(xcl);
                const int   x1i  = min(x0 + 1, W - 1);
                const float lx   = xcl - (float)x0;
                const float hx   = 1.0f - lx;

                const float m   = (vy && vx) ? 1.0f : 0.0f;
                const float w00 = m * hy * hx;
                const float w01 = m * hy * lx;
                const float w10 = m * ly * hx;
                const float w11 = m * ly * lx;

                const unsigned int u00 = *(const unsigned int*)(feat + ((size_t)(y0  * W + x0 )) * NCH + 2 * cp);
                const unsigned int u01 = *(const unsigned int*)(feat + ((size_t)(y0  * W + x1i)) * NCH + 2 * cp);
                const unsigned int u10 = *(const unsigned int*)(feat + ((size_t)(y1i * W + x0 )) * NCH + 2 * cp);
                const unsigned int u11 = *(const unsigned int*)(feat + ((size_t)(y1i * W + x1i)) * NCH + 2 * cp);

                acc0 += w00 * __uint_as_float(u00 << 16)
                      + w01 * __uint_as_float(u01 << 16)
                      + w10 * __uint_as_float(u10 << 16)
                      + w11 * __uint_as_float(u11 << 16);
                acc1 += w00 * __uint_as_float(u00 & 0xffff0000u)
                      + w01 * __uint_as_float(u01 & 0xffff0000u)
                      + w10 * __uint_as_float(u10 & 0xffff0000u)
                      + w11 * __uint_as_float(u11 & 0xffff0000u);
            }
        }
        lds[bin * 258 + 2 * cp]     = acc0 * 0.25f;
        lds[bin * 258 + 2 * cp + 1] = acc1 * 0.25f;
    }

    __syncthreads();

    float* __restrict__ o = out + (size_t)r * (NCH * 49);
#pragma unroll
    for (int i = 0; i < 49; ++i) {
        const int j  = i * NCH + t;       // 0..12543
        const int ch = j / 49;
        const int bn = j - ch * 49;
        o[j] = lds[bn * 258 + ch];
    }
}

// ---------------------------------------------------------------------------
// Fallback (round-1 kernel) if d_ws is too small for the NHWC bf16 copy.
// ---------------------------------------------------------------------------
__global__ __launch_bounds__(256) void roi_align_fpn_kernel(
    const float* __restrict__ f0, const float* __restrict__ f1,
    const float* __restrict__ f2, const float* __restrict__ f3,
    const float* __restrict__ boxes, const int* __restrict__ bidx,
    float* __restrict__ out)
{
    const int r   = blockIdx.x;
    const int bin = blockIdx.y;
    const int c   = threadIdx.x;
    const int py  = bin / RES;
    const int px  = bin - py * RES;

    const float bx1 = boxes[r * 4 + 0];
    const float by1 = boxes[r * 4 + 1];
    const float bx2 = boxes[r * 4 + 2];
    const float by2 = boxes[r * 4 + 3];

    const float area = fmaxf(bx2 - bx1, 0.0f) * fmaxf(by2 - by1, 0.0f);
    const float s    = sqrtf(area);
    const float lvlf = floorf(4.0f + log2f(s / 224.0f + 1e-6f));
    const int   lvl  = (int)(fminf(fmaxf(lvlf, 2.0f), 5.0f)) - 2;

    const float scales[4] = {0.25f, 0.125f, 0.0625f, 0.03125f};
    const int   Hs[4]     = {200, 100, 50, 25};
    const float* feats[4] = {f0, f1, f2, f3};

    const float scale = scales[lvl];
    const int   H     = Hs[lvl];
    const int   W     = H;
    const float* feat = feats[lvl];

    const int b = bidx[r];

    const float x1 = bx1 * scale;
    const float y1 = by1 * scale;
    const float roi_w = fmaxf(bx2 * scale - x1, 1.0f);
    const float roi_h = fmaxf(by2 * scale - y1, 1.0f);
    const float bw = roi_w * (1.0f / RES);
    const float bh = roi_h * (1.0f / RES);

    const float* __restrict__ fc = feat + (size_t)(b * NCH + c) * H * W;

    float acc = 0.0f;
#pragma unroll
    for (int sy = 0; sy < 2; ++sy) {
        const float pyf = (float)py + ((float)sy + 0.5f) * 0.5f;
        const float ys  = y1 + pyf * bh;
        const bool  vy  = (ys >= -1.0f) && (ys <= (float)H);
        const float ycl = fminf(fmaxf(ys, 0.0f), (float)(H - 1));
        const int   y0  = (int)floorf(ycl);
        const int   y1i = min(y0 + 1, H - 1);
        const float ly  = ycl - (float)y0;
        const float hy  = 1.0f - ly;
#pragma unroll
        for (int sx = 0; sx < 2; ++sx) {
            const float pxf = (float)px + ((float)sx + 0.5f) * 0.5f;
            const float xs  = x1 + pxf * bw;
            const bool  vx  = (xs >= -1.0f) && (xs <= (float)W);
            const float xcl = fminf(fmaxf(xs, 0.0f), (float)(W - 1));
            const int   x0  = (int)floorf(xcl);
            const int   x1i = min(x0 + 1, W - 1);
            const float lx  = xcl - (float)x0;
            const float hx  = 1.0f - lx;

            const float v00 = fc[y0  * W + x0 ];
            const float v01 = fc[y0  * W + x1i];
            const float v10 = fc[y1i * W + x0 ];
            const float v11 = fc[y1i * W + x1i];

            const float v = v00 * (hy * hx) + v01 * (hy * lx)
                          + v10 * (ly * hx) + v11 * (ly * lx);
            if (vy && vx) acc += v;
        }
    }

    out[((size_t)r * NCH + c) * (RES * RES) + bin] = acc * 0.25f;
}

extern "C" void kernel_launch(void* const* d_in, const int* in_sizes, int n_in,
                              void* d_out, int out_size, void* d_ws, size_t ws_size,
                              hipStream_t stream)
{
    const float* f0    = (const float*)d_in[0];
    const float* f1    = (const float*)d_in[1];
    const float* f2    = (const float*)d_in[2];
    const float* f3    = (const float*)d_in[3];
    const float* boxes = (const float*)d_in[4];
    const int*   bidx  = (const int*)d_in[5];
    float* out = (float*)d_out;

    const int R = in_sizes[4] / 4;  // 512 boxes

    const size_t need = 27200000ull * sizeof(unsigned short);  // bf16 NHWC copy

    if (ws_size >= need) {
        unsigned short* ws = (unsigned short*)d_ws;
        const int HWs[4]  = {40000, 10000, 2500, 625};
        const float* srcs[4] = {f0, f1, f2, f3};
        const size_t offs[4] = {0u, 20480000u, 25600000u, 26880000u};
        for (int l = 0; l < 4; ++l) {
            dim3 grid((HWs[l] + 31) / 32, NCH / 32, 2);
            dim3 block(32, 8);
            transpose_chw_hwc_bf16<<<grid, block, 0, stream>>>(srcs[l], ws + offs[l], HWs[l]);
        }
        roi_gather_nhwc_bf16<<<dim3(R), dim3(NCH), 0, stream>>>(ws, boxes, bidx, out);
    } else {
        dim3 grid(R, RES * RES);
        roi_align_fpn_kernel<<<grid, dim3(NCH), 0, stream>>>(f0, f1, f2, f3, boxes, bidx, out);
    }
}

// Round 4
// 53.347 us; speedup vs baseline: 8.7569x; 1.2110x over previous
//
#include <hip/hip_runtime.h>
#include <hip/hip_bf16.h>

#define RES 7
#define NCH 256

__device__ __forceinline__ unsigned short f32_to_bf16_rne(float f) {
    unsigned int u = __float_as_uint(f);
    u += 0x7fffu + ((u >> 16) & 1u);
    return (unsigned short)(u >> 16);
}

// ---------------------------------------------------------------------------
// Pass 1 (single launch): NCHW fp32 -> NHWC bf16 transpose, all 4 levels.
// Grid: x = hw-tile (prefix-partitioned over levels), y = c-tile (8), z = batch.
// ---------------------------------------------------------------------------
__global__ __launch_bounds__(256) void transpose_all_bf16(
    const float* __restrict__ f0, const float* __restrict__ f1,
    const float* __restrict__ f2, const float* __restrict__ f3,
    unsigned short* __restrict__ ws)
{
    __shared__ float tile[32][33];

    // hw-tile prefix: f0:1250, f1:313, f2:79, f3:20  (total 1662)
    const int x = blockIdx.x;
    const int l = (x >= 1250) + (x >= 1563) + (x >= 1642);

    const int base = (l == 0) ? 0 : (l == 1) ? 1250 : (l == 2) ? 1563 : 1642;
    const int HW   = (l == 0) ? 40000 : (l == 1) ? 10000 : (l == 2) ? 2500 : 625;
    const float* __restrict__ src =
        (l == 0) ? f0 : (l == 1) ? f1 : (l == 2) ? f2 : f3;
    const size_t doff = (l == 0) ? 0u : (l == 1) ? 20480000u
                      : (l == 2) ? 25600000u : 26880000u;

    const int b   = blockIdx.z;
    const int hw0 = (x - base) * 32;
    const int c0  = blockIdx.y * 32;
    const int tx  = threadIdx.x;   // 0..31
    const int ty  = threadIdx.y;   // 0..7

    const float* __restrict__ s    = src + (size_t)b * NCH * HW;
    unsigned short* __restrict__ d = ws + doff + (size_t)b * HW * NCH;

    const int hw_r = hw0 + tx;
#pragma unroll
    for (int i = 0; i < 32; i += 8) {
        const int c = c0 + ty + i;
        if (hw_r < HW) tile[ty + i][tx] = s[(size_t)c * HW + hw_r];
    }
    __syncthreads();
    const int c_w = c0 + tx;
#pragma unroll
    for (int i = 0; i < 32; i += 8) {
        const int hw = hw0 + ty + i;
        if (hw < HW) d[(size_t)hw * NCH + c_w] = f32_to_bf16_rne(tile[tx][ty + i]);
    }
}

// ---------------------------------------------------------------------------
// Pass 2: one block per ROI, 512 threads (8 waves).
// Lane = channel-quad (4 bf16 ch via one uint2, 8B/lane -> 512B/wave per tap);
// bins strided over 8 groups. Output written fully coalesced via LDS.
// ---------------------------------------------------------------------------
__global__ __launch_bounds__(512) void roi_gather_nhwc_bf16(
    const unsigned short* __restrict__ ws,
    const float* __restrict__ boxes, const int* __restrict__ bidx,
    float* __restrict__ out)
{
    __shared__ float lds[49 * 260];

    const int r   = blockIdx.x;
    const int t   = threadIdx.x;
    const int cq  = t & 63;        // channels 4cq .. 4cq+3
    const int grp = t >> 6;        // 0..7

    const float bx1 = boxes[r * 4 + 0];
    const float by1 = boxes[r * 4 + 1];
    const float bx2 = boxes[r * 4 + 2];
    const float by2 = boxes[r * 4 + 3];

    const float area = fmaxf(bx2 - bx1, 0.0f) * fmaxf(by2 - by1, 0.0f);
    const float s    = sqrtf(area);
    const float lvlf = floorf(4.0f + log2f(s / 224.0f + 1e-6f));
    const int   lvl  = (int)(fminf(fmaxf(lvlf, 2.0f), 5.0f)) - 2;

    float scale; int H; size_t off;
    if      (lvl == 0) { scale = 0.25f;    H = 200; off = 0u; }
    else if (lvl == 1) { scale = 0.125f;   H = 100; off = 20480000u; }
    else if (lvl == 2) { scale = 0.0625f;  H = 50;  off = 25600000u; }
    else               { scale = 0.03125f; H = 25;  off = 26880000u; }
    const int W = H;

    const int b = bidx[r];
    const unsigned short* __restrict__ feat = ws + off + (size_t)b * H * W * NCH;

    const float x1 = bx1 * scale;
    const float y1 = by1 * scale;
    const float roi_w = fmaxf(bx2 * scale - x1, 1.0f);
    const float roi_h = fmaxf(by2 * scale - y1, 1.0f);
    const float bw = roi_w * (1.0f / RES);
    const float bh = roi_h * (1.0f / RES);

    for (int bin = grp; bin < 49; bin += 8) {
        const int py = bin / 7;
        const int px = bin - py * 7;

        float acc0 = 0.0f, acc1 = 0.0f, acc2 = 0.0f, acc3 = 0.0f;
#pragma unroll
        for (int sy = 0; sy < 2; ++sy) {
            const float pyf = (float)py + ((float)sy + 0.5f) * 0.5f;
            const float ysmp = y1 + pyf * bh;
            const bool  vy   = (ysmp >= -1.0f) && (ysmp <= (float)H);
            const float ycl  = fminf(fmaxf(ysmp, 0.0f), (float)(H - 1));
            const int   y0   = (int)floorf(ycl);
            const int   y1i  = min(y0 + 1, H - 1);
            const float ly   = ycl - (float)y0;
            const float hy   = 1.0f - ly;
#pragma unroll
            for (int sx = 0; sx < 2; ++sx) {
                const float pxf = (float)px + ((float)sx + 0.5f) * 0.5f;
                const float xsmp = x1 + pxf * bw;
                const bool  vx   = (xsmp >= -1.0f) && (xsmp <= (float)W);
                const float xcl  = fminf(fmaxf(xsmp, 0.0f), (float)(W - 1));
                const int   x0   = (int)floorf(xcl);
                const int   x1i  = min(x0 + 1, W - 1);
                const float lx   = xcl - (float)x0;
                const float hx   = 1.0f - lx;

                const float m   = (vy && vx) ? 1.0f : 0.0f;
                const float w00 = m * hy * hx;
                const float w01 = m * hy * lx;
                const float w10 = m * ly * hx;
                const float w11 = m * ly * lx;

                const uint2 u00 = *(const uint2*)(feat + ((size_t)(y0  * W + x0 )) * NCH + 4 * cq);
                const uint2 u01 = *(const uint2*)(feat + ((size_t)(y0  * W + x1i)) * NCH + 4 * cq);
                const uint2 u10 = *(const uint2*)(feat + ((size_t)(y1i * W + x0 )) * NCH + 4 * cq);
                const uint2 u11 = *(const uint2*)(feat + ((size_t)(y1i * W + x1i)) * NCH + 4 * cq);

                acc0 += w00 * __uint_as_float(u00.x << 16)
                      + w01 * __uint_as_float(u01.x << 16)
                      + w10 * __uint_as_float(u10.x << 16)
                      + w11 * __uint_as_float(u11.x << 16);
                acc1 += w00 * __uint_as_float(u00.x & 0xffff0000u)
                      + w01 * __uint_as_float(u01.x & 0xffff0000u)
                      + w10 * __uint_as_float(u10.x & 0xffff0000u)
                      + w11 * __uint_as_float(u11.x & 0xffff0000u);
                acc2 += w00 * __uint_as_float(u00.y << 16)
                      + w01 * __uint_as_float(u01.y << 16)
                      + w10 * __uint_as_float(u10.y << 16)
                      + w11 * __uint_as_float(u11.y << 16);
                acc3 += w00 * __uint_as_float(u00.y & 0xffff0000u)
                      + w01 * __uint_as_float(u01.y & 0xffff0000u)
                      + w10 * __uint_as_float(u10.y & 0xffff0000u)
                      + w11 * __uint_as_float(u11.y & 0xffff0000u);
            }
        }
        float4* dst = (float4*)&lds[bin * 260 + 4 * cq];
        *dst = make_float4(acc0 * 0.25f, acc1 * 0.25f, acc2 * 0.25f, acc3 * 0.25f);
    }

    __syncthreads();

    float* __restrict__ o = out + (size_t)r * (NCH * 49);
    for (int i = t; i < NCH * 49; i += 512) {
        const int ch = i / 49;
        const int bn = i - ch * 49;
        o[i] = lds[bn * 260 + ch];
    }
}

// ---------------------------------------------------------------------------
// Fallback (round-1 kernel) if d_ws is too small for the NHWC bf16 copy.
// ---------------------------------------------------------------------------
__global__ __launch_bounds__(256) void roi_align_fpn_kernel(
    const float* __restrict__ f0, const float* __restrict__ f1,
    const float* __restrict__ f2, const float* __restrict__ f3,
    const float* __restrict__ boxes, const int* __restrict__ bidx,
    float* __restrict__ out)
{
    const int r   = blockIdx.x;
    const int bin = blockIdx.y;
    const int c   = threadIdx.x;
    const int py  = bin / RES;
    const int px  = bin - py * RES;

    const float bx1 = boxes[r * 4 + 0];
    const float by1 = boxes[r * 4 + 1];
    const float bx2 = boxes[r * 4 + 2];
    const float by2 = boxes[r * 4 + 3];

    const float area = fmaxf(bx2 - bx1, 0.0f) * fmaxf(by2 - by1, 0.0f);
    const float s    = sqrtf(area);
    const float lvlf = floorf(4.0f + log2f(s / 224.0f + 1e-6f));
    const int   lvl  = (int)(fminf(fmaxf(lvlf, 2.0f), 5.0f)) - 2;

    const float scales[4] = {0.25f, 0.125f, 0.0625f, 0.03125f};
    const int   Hs[4]     = {200, 100, 50, 25};
    const float* feats[4] = {f0, f1, f2, f3};

    const float scale = scales[lvl];
    const int   H     = Hs[lvl];
    const int   W     = H;
    const float* feat = feats[lvl];

    const int b = bidx[r];

    const float x1 = bx1 * scale;
    const float y1 = by1 * scale;
    const float roi_w = fmaxf(bx2 * scale - x1, 1.0f);
    const float roi_h = fmaxf(by2 * scale - y1, 1.0f);
    const float bw = roi_w * (1.0f / RES);
    const float bh = roi_h * (1.0f / RES);

    const float* __restrict__ fc = feat + (size_t)(b * NCH + c) * H * W;

    float acc = 0.0f;
#pragma unroll
    for (int sy = 0; sy < 2; ++sy) {
        const float pyf = (float)py + ((float)sy + 0.5f) * 0.5f;
        const float ys  = y1 + pyf * bh;
        const bool  vy  = (ys >= -1.0f) && (ys <= (float)H);
        const float ycl = fminf(fmaxf(ys, 0.0f), (float)(H - 1));
        const int   y0  = (int)floorf(ycl);
        const int   y1i = min(y0 + 1, H - 1);
        const float ly  = ycl - (float)y0;
        const float hy  = 1.0f - ly;
#pragma unroll
        for (int sx = 0; sx < 2; ++sx) {
            const float pxf = (float)px + ((float)sx + 0.5f) * 0.5f;
            const float xs  = x1 + pxf * bw;
            const bool  vx  = (xs >= -1.0f) && (xs <= (float)W);
            const float xcl = fminf(fmaxf(xs, 0.0f), (float)(W - 1));
            const int   x0  = (int)floorf(xcl);
            const int   x1i = min(x0 + 1, W - 1);
            const float lx  = xcl - (float)x0;
            const float hx  = 1.0f - lx;

            const float v00 = fc[y0  * W + x0 ];
            const float v01 = fc[y0  * W + x1i];
            const float v10 = fc[y1i * W + x0 ];
            const float v11 = fc[y1i * W + x1i];

            const float v = v00 * (hy * hx) + v01 * (hy * lx)
                          + v10 * (ly * hx) + v11 * (ly * lx);
            if (vy && vx) acc += v;
        }
    }

    out[((size_t)r * NCH + c) * (RES * RES) + bin] = acc * 0.25f;
}

extern "C" void kernel_launch(void* const* d_in, const int* in_sizes, int n_in,
                              void* d_out, int out_size, void* d_ws, size_t ws_size,
                              hipStream_t stream)
{
    const float* f0    = (const float*)d_in[0];
    const float* f1    = (const float*)d_in[1];
    const float* f2    = (const float*)d_in[2];
    const float* f3    = (const float*)d_in[3];
    const float* boxes = (const float*)d_in[4];
    const int*   bidx  = (const int*)d_in[5];
    float* out = (float*)d_out;

    const int R = in_sizes[4] / 4;  // 512 boxes

    const size_t need = 27200000ull * sizeof(unsigned short);  // bf16 NHWC copy

    if (ws_size >= need) {
        unsigned short* ws = (unsigned short*)d_ws;
        dim3 tgrid(1662, 8, 2);     // hw-tiles (prefix over levels), c-tiles, batch
        dim3 tblock(32, 8);
        transpose_all_bf16<<<tgrid, tblock, 0, stream>>>(f0, f1, f2, f3, ws);
        roi_gather_nhwc_bf16<<<dim3(R), dim3(512), 0, stream>>>(ws, boxes, bidx, out);
    } else {
        dim3 grid(R, RES * RES);
        roi_align_fpn_kernel<<<grid, dim3(NCH), 0, stream>>>(f0, f1, f2, f3, boxes, bidx, out);
    }
}

// Round 5
// 51.007 us; speedup vs baseline: 9.1588x; 1.0459x over previous
//
#include <hip/hip_runtime.h>
#include <hip/hip_bf16.h>

#define RES 7
#define NCH 256

__device__ __forceinline__ unsigned short f32_to_bf16_rne(float f) {
    unsigned int u = __float_as_uint(f);
    u += 0x7fffu + ((u >> 16) & 1u);
    return (unsigned short)(u >> 16);
}

// ---------------------------------------------------------------------------
// Pass 1: NCHW fp32 -> NHWC bf16, all 4 levels, one launch.
// Tile = 64 hw x 256 c, 512 threads. Reads: float4 along hw. Writes: one full
// 512B output row (256 bf16 ch) per wave instruction -> no partial lines.
// Grid flattened + bijective XCD-chunk swizzle (1664 = 8 x 208).
// ---------------------------------------------------------------------------
__global__ __launch_bounds__(512) void transpose_all_bf16_v2(
    const float* __restrict__ f0, const float* __restrict__ f1,
    const float* __restrict__ f2, const float* __restrict__ f3,
    unsigned short* __restrict__ ws)
{
    __shared__ unsigned short lds[64 * 260];   // [hw][c], 4-col pad

    int id = blockIdx.x;                       // 0..1663
    id = (id & 7) * 208 + (id >> 3);           // XCD chunk swizzle (1664%8==0)

    const int b = (id >= 832) ? 1 : 0;
    const int x = b ? (id - 832) : id;         // 0..831 hw-tile across levels

    // per-level hw-tile prefix: f0:625, f1:157, f2:40, f3:10  (total 832)
    const int l = (x >= 625) + (x >= 782) + (x >= 822);
    const int base = (l == 0) ? 0 : (l == 1) ? 625 : (l == 2) ? 782 : 822;
    const int HW   = (l == 0) ? 40000 : (l == 1) ? 10000 : (l == 2) ? 2500 : 625;
    const float* __restrict__ src =
        (l == 0) ? f0 : (l == 1) ? f1 : (l == 2) ? f2 : f3;
    const size_t doff = (l == 0) ? 0u : (l == 1) ? 20480000u
                      : (l == 2) ? 25600000u : 26880000u;

    const int hw0 = (x - base) * 64;
    const float* __restrict__ s    = src + (size_t)b * NCH * HW;
    unsigned short* __restrict__ d = ws + doff + (size_t)b * HW * NCH;

    const int t  = threadIdx.x;
    const int hq = t & 15;      // hw quad: hw0 + 4*hq .. +3
    const int cr = t >> 4;      // 0..31
    const int hwq = hw0 + 4 * hq;

#pragma unroll
    for (int g = 0; g < 8; ++g) {
        const int c = cr + 32 * g;
        unsigned short v0, v1, v2, v3;
        if (hwq + 3 < HW) {
            const float4 f = *(const float4*)(s + (size_t)c * HW + hwq);
            v0 = f32_to_bf16_rne(f.x); v1 = f32_to_bf16_rne(f.y);
            v2 = f32_to_bf16_rne(f.z); v3 = f32_to_bf16_rne(f.w);
        } else {
            v0 = (hwq + 0 < HW) ? f32_to_bf16_rne(s[(size_t)c * HW + hwq + 0]) : 0;
            v1 = (hwq + 1 < HW) ? f32_to_bf16_rne(s[(size_t)c * HW + hwq + 1]) : 0;
            v2 = (hwq + 2 < HW) ? f32_to_bf16_rne(s[(size_t)c * HW + hwq + 2]) : 0;
            v3 = (hwq + 3 < HW) ? f32_to_bf16_rne(s[(size_t)c * HW + hwq + 3]) : 0;
        }
        lds[(4 * hq + 0) * 260 + c] = v0;
        lds[(4 * hq + 1) * 260 + c] = v1;
        lds[(4 * hq + 2) * 260 + c] = v2;
        lds[(4 * hq + 3) * 260 + c] = v3;
    }
    __syncthreads();

    const int w  = t >> 6;      // wave 0..7
    const int ln = t & 63;      // lane -> channels 4*ln..4*ln+3
#pragma unroll
    for (int j = 0; j < 8; ++j) {
        const int hwl = w + 8 * j;
        const int hw  = hw0 + hwl;
        if (hw < HW) {
            const uint2 p = *(const uint2*)&lds[hwl * 260 + 4 * ln];
            *(uint2*)(d + (size_t)hw * NCH + 4 * ln) = p;
        }
    }
}

// ---------------------------------------------------------------------------
// Pass 2: one block per ROI, 512 threads (8 waves).
// Lane = channel-quad (uint2 = 4 bf16); bins strided over 8 groups.
// ---------------------------------------------------------------------------
__global__ __launch_bounds__(512) void roi_gather_nhwc_bf16(
    const unsigned short* __restrict__ ws,
    const float* __restrict__ boxes, const int* __restrict__ bidx,
    float* __restrict__ out)
{
    __shared__ float lds[49 * 260];

    const int r   = blockIdx.x;
    const int t   = threadIdx.x;
    const int cq  = t & 63;
    const int grp = t >> 6;

    const float bx1 = boxes[r * 4 + 0];
    const float by1 = boxes[r * 4 + 1];
    const float bx2 = boxes[r * 4 + 2];
    const float by2 = boxes[r * 4 + 3];

    const float area = fmaxf(bx2 - bx1, 0.0f) * fmaxf(by2 - by1, 0.0f);
    const float s    = sqrtf(area);
    const float lvlf = floorf(4.0f + log2f(s / 224.0f + 1e-6f));
    const int   lvl  = (int)(fminf(fmaxf(lvlf, 2.0f), 5.0f)) - 2;

    float scale; int H; size_t off;
    if      (lvl == 0) { scale = 0.25f;    H = 200; off = 0u; }
    else if (lvl == 1) { scale = 0.125f;   H = 100; off = 20480000u; }
    else if (lvl == 2) { scale = 0.0625f;  H = 50;  off = 25600000u; }
    else               { scale = 0.03125f; H = 25;  off = 26880000u; }
    const int W = H;

    const int b = bidx[r];
    const unsigned short* __restrict__ feat = ws + off + (size_t)b * H * W * NCH;

    const float x1 = bx1 * scale;
    const float y1 = by1 * scale;
    const float roi_w = fmaxf(bx2 * scale - x1, 1.0f);
    const float roi_h = fmaxf(by2 * scale - y1, 1.0f);
    const float bw = roi_w * (1.0f / RES);
    const float bh = roi_h * (1.0f / RES);

    for (int bin = grp; bin < 49; bin += 8) {
        const int py = bin / 7;
        const int px = bin - py * 7;

        float acc0 = 0.0f, acc1 = 0.0f, acc2 = 0.0f, acc3 = 0.0f;
#pragma unroll
        for (int sy = 0; sy < 2; ++sy) {
            const float pyf = (float)py + ((float)sy + 0.5f) * 0.5f;
            const float ysmp = y1 + pyf * bh;
            const bool  vy   = (ysmp >= -1.0f) && (ysmp <= (float)H);
            const float ycl  = fminf(fmaxf(ysmp, 0.0f), (float)(H - 1));
            const int   y0   = (int)floorf(ycl);
            const int   y1i  = min(y0 + 1, H - 1);
            const float ly   = ycl - (float)y0;
            const float hy   = 1.0f - ly;
#pragma unroll
            for (int sx = 0; sx < 2; ++sx) {
                const float pxf = (float)px + ((float)sx + 0.5f) * 0.5f;
                const float xsmp = x1 + pxf * bw;
                const bool  vx   = (xsmp >= -1.0f) && (xsmp <= (float)W);
                const float xcl  = fminf(fmaxf(xsmp, 0.0f), (float)(W - 1));
                const int   x0   = (int)floorf(xcl);
                const int   x1i  = min(x0 + 1, W - 1);
                const float lx   = xcl - (float)x0;
                const float hx   = 1.0f - lx;

                const float m   = (vy && vx) ? 1.0f : 0.0f;
                const float w00 = m * hy * hx;
                const float w01 = m * hy * lx;
                const float w10 = m * ly * hx;
                const float w11 = m * ly * lx;

                const uint2 u00 = *(const uint2*)(feat + ((size_t)(y0  * W + x0 )) * NCH + 4 * cq);
                const uint2 u01 = *(const uint2*)(feat + ((size_t)(y0  * W + x1i)) * NCH + 4 * cq);
                const uint2 u10 = *(const uint2*)(feat + ((size_t)(y1i * W + x0 )) * NCH + 4 * cq);
                const uint2 u11 = *(const uint2*)(feat + ((size_t)(y1i * W + x1i)) * NCH + 4 * cq);

                acc0 += w00 * __uint_as_float(u00.x << 16)
                      + w01 * __uint_as_float(u01.x << 16)
                      + w10 * __uint_as_float(u10.x << 16)
                      + w11 * __uint_as_float(u11.x << 16);
                acc1 += w00 * __uint_as_float(u00.x & 0xffff0000u)
                      + w01 * __uint_as_float(u01.x & 0xffff0000u)
                      + w10 * __uint_as_float(u10.x & 0xffff0000u)
                      + w11 * __uint_as_float(u11.x & 0xffff0000u);
                acc2 += w00 * __uint_as_float(u00.y << 16)
                      + w01 * __uint_as_float(u01.y << 16)
                      + w10 * __uint_as_float(u10.y << 16)
                      + w11 * __uint_as_float(u11.y << 16);
                acc3 += w00 * __uint_as_float(u00.y & 0xffff0000u)
                      + w01 * __uint_as_float(u01.y & 0xffff0000u)
                      + w10 * __uint_as_float(u10.y & 0xffff0000u)
                      + w11 * __uint_as_float(u11.y & 0xffff0000u);
            }
        }
        float4* dst = (float4*)&lds[bin * 260 + 4 * cq];
        *dst = make_float4(acc0 * 0.25f, acc1 * 0.25f, acc2 * 0.25f, acc3 * 0.25f);
    }

    __syncthreads();

    float* __restrict__ o = out + (size_t)r * (NCH * 49);
    for (int i = t; i < NCH * 49; i += 512) {
        const int ch = i / 49;
        const int bn = i - ch * 49;
        o[i] = lds[bn * 260 + ch];
    }
}

// ---------------------------------------------------------------------------
// Fallback (round-1 kernel) if d_ws is too small for the NHWC bf16 copy.
// ---------------------------------------------------------------------------
__global__ __launch_bounds__(256) void roi_align_fpn_kernel(
    const float* __restrict__ f0, const float* __restrict__ f1,
    const float* __restrict__ f2, const float* __restrict__ f3,
    const float* __restrict__ boxes, const int* __restrict__ bidx,
    float* __restrict__ out)
{
    const int r   = blockIdx.x;
    const int bin = blockIdx.y;
    const int c   = threadIdx.x;
    const int py  = bin / RES;
    const int px  = bin - py * RES;

    const float bx1 = boxes[r * 4 + 0];
    const float by1 = boxes[r * 4 + 1];
    const float bx2 = boxes[r * 4 + 2];
    const float by2 = boxes[r * 4 + 3];

    const float area = fmaxf(bx2 - bx1, 0.0f) * fmaxf(by2 - by1, 0.0f);
    const float s    = sqrtf(area);
    const float lvlf = floorf(4.0f + log2f(s / 224.0f + 1e-6f));
    const int   lvl  = (int)(fminf(fmaxf(lvlf, 2.0f), 5.0f)) - 2;

    const float scales[4] = {0.25f, 0.125f, 0.0625f, 0.03125f};
    const int   Hs[4]     = {200, 100, 50, 25};
    const float* feats[4] = {f0, f1, f2, f3};

    const float scale = scales[lvl];
    const int   H     = Hs[lvl];
    const int   W     = H;
    const float* feat = feats[lvl];

    const int b = bidx[r];

    const float x1 = bx1 * scale;
    const float y1 = by1 * scale;
    const float roi_w = fmaxf(bx2 * scale - x1, 1.0f);
    const float roi_h = fmaxf(by2 * scale - y1, 1.0f);
    const float bw = roi_w * (1.0f / RES);
    const float bh = roi_h * (1.0f / RES);

    const float* __restrict__ fc = feat + (size_t)(b * NCH + c) * H * W;

    float acc = 0.0f;
#pragma unroll
    for (int sy = 0; sy < 2; ++sy) {
        const float pyf = (float)py + ((float)sy + 0.5f) * 0.5f;
        const float ys  = y1 + pyf * bh;
        const bool  vy  = (ys >= -1.0f) && (ys <= (float)H);
        const float ycl = fminf(fmaxf(ys, 0.0f), (float)(H - 1));
        const int   y0  = (int)floorf(ycl);
        const int   y1i = min(y0 + 1, H - 1);
        const float ly  = ycl - (float)y0;
        const float hy  = 1.0f - ly;
#pragma unroll
        for (int sx = 0; sx < 2; ++sx) {
            const float pxf = (float)px + ((float)sx + 0.5f) * 0.5f;
            const float xs  = x1 + pxf * bw;
            const bool  vx  = (xs >= -1.0f) && (xs <= (float)W);
            const float xcl = fminf(fmaxf(xs, 0.0f), (float)(W - 1));
            const int   x0  = (int)floorf(xcl);
            const int   x1i = min(x0 + 1, W - 1);
            const float lx  = xcl - (float)x0;
            const float hx  = 1.0f - lx;

            const float v00 = fc[y0  * W + x0 ];
            const float v01 = fc[y0  * W + x1i];
            const float v10 = fc[y1i * W + x0 ];
            const float v11 = fc[y1i * W + x1i];

            const float v = v00 * (hy * hx) + v01 * (hy * lx)
                          + v10 * (ly * hx) + v11 * (ly * lx);
            if (vy && vx) acc += v;
        }
    }

    out[((size_t)r * NCH + c) * (RES * RES) + bin] = acc * 0.25f;
}

extern "C" void kernel_launch(void* const* d_in, const int* in_sizes, int n_in,
                              void* d_out, int out_size, void* d_ws, size_t ws_size,
                              hipStream_t stream)
{
    const float* f0    = (const float*)d_in[0];
    const float* f1    = (const float*)d_in[1];
    const float* f2    = (const float*)d_in[2];
    const float* f3    = (const float*)d_in[3];
    const float* boxes = (const float*)d_in[4];
    const int*   bidx  = (const int*)d_in[5];
    float* out = (float*)d_out;

    const int R = in_sizes[4] / 4;  // 512 boxes

    const size_t need = 27200000ull * sizeof(unsigned short);  // bf16 NHWC copy

    if (ws_size >= need) {
        unsigned short* ws = (unsigned short*)d_ws;
        transpose_all_bf16_v2<<<dim3(1664), dim3(512), 0, stream>>>(f0, f1, f2, f3, ws);
        roi_gather_nhwc_bf16<<<dim3(R), dim3(512), 0, stream>>>(ws, boxes, bidx, out);
    } else {
        dim3 grid(R, RES * RES);
        roi_align_fpn_kernel<<<grid, dim3(NCH), 0, stream>>>(f0, f1, f2, f3, boxes, bidx, out);
    }
}